// Round 3
// baseline (1925.162 us; speedup 1.0000x reference)
//
#include <hip/hip_runtime.h>
#include <hip/hip_bf16.h>
#include <cstddef>

// Problem dims (fixed)
#define BB 256
#define CC 512
#define SS 128      // FH*FW = 8*16
#define HH 512
#define VV 64
#define LL 24       // sequence length; steps = 23

typedef unsigned short ush;
typedef __attribute__((ext_vector_type(8))) short short8;
typedef __attribute__((ext_vector_type(4))) float f32x4;

__device__ __forceinline__ float wave_sum(float v) {
#pragma unroll
    for (int off = 32; off > 0; off >>= 1) v += __shfl_xor(v, off);
    return v;
}
__device__ __forceinline__ float wave_max(float v) {
#pragma unroll
    for (int off = 32; off > 0; off >>= 1) v = fmaxf(v, __shfl_xor(v, off));
    return v;
}
__device__ __forceinline__ float sigm(float x) { return 1.0f / (1.0f + expf(-x)); }
__device__ __forceinline__ ush f2bf(float f) {
    unsigned u = __float_as_uint(f);
    u += 0x7FFFu + ((u >> 16) & 1u);
    return (ush)(u >> 16);
}
__device__ __forceinline__ float bf2f(ush b) {
    return __uint_as_float(((unsigned)b) << 16);
}
__device__ __forceinline__ float bfl(unsigned u) { return __uint_as_float(u << 16); }
__device__ __forceinline__ float bfh(unsigned u) { return __uint_as_float(u & 0xFFFF0000u); }
__device__ __forceinline__ unsigned pack2(float a, float b) {
    return (unsigned)f2bf(a) | ((unsigned)f2bf(b) << 16);
}

// ---------------------------------------------------------------------------
__global__ __launch_bounds__(256) void init_kernel(const float* __restrict__ init_state,
                                                   float* __restrict__ h0,
                                                   float* __restrict__ h1,
                                                   ush* __restrict__ h0b,
                                                   ush* __restrict__ h1b,
                                                   float* __restrict__ acc) {
    int idx = blockIdx.x * 256 + threadIdx.x;
    if (idx < BB * HH) {
        float a = init_state[idx & (HH - 1)];
        float b = init_state[HH + (idx & (HH - 1))];
        h0[idx] = a; h1[idx] = b;
        h0b[idx] = f2bf(a); h1b[idx] = f2bf(b);
    }
    if (idx < 2) acc[idx] = 0.0f;
}

// ---------------------------------------------------------------------------
// Multi-segment fp32->bf16 convert: all plain weight conversions in one launch.
struct CvArgs {
    const float* src[6];
    ush* dst[6];
    int end[6];    // cumulative block counts; each block = 256 float4
};
__global__ __launch_bounds__(256) void conv_multi(CvArgs A) {
    int blk = blockIdx.x;
    int s = 0;
    while (s < 5 && blk >= A.end[s]) s++;
    int base = s ? A.end[s - 1] : 0;
    int i = (blk - base) * 256 + threadIdx.x;
    float4 v = ((const float4*)A.src[s])[i];
    uint2 o;
    o.x = pack2(v.x, v.y);
    o.y = pack2(v.z, v.w);
    ((uint2*)A.dst[s])[i] = o;
}

// ---------------------------------------------------------------------------
// Transpose-pack: src fp32 [N=512][K] -> dst uint2 [K/4][512], elem (k4,n) =
// {pack(w[n][4k4],w[n][4k4+1]), pack(w[n][4k4+2],w[n][4k4+3])}.
__global__ __launch_bounds__(256) void tp_conv(const float* __restrict__ src,
                                               uint2* __restrict__ dst, int K) {
    int n0 = blockIdx.x * 64, k0 = blockIdx.y * 64;
    __shared__ ush til[64][68];
    int tid = threadIdx.x;
#pragma unroll
    for (int i = 0; i < 4; i++) {
        int idx = i * 256 + tid;
        int r = idx >> 4, c4 = idx & 15;
        float4 v = ((const float4*)(src + (size_t)(n0 + r) * K + k0))[c4];
        til[r][c4 * 4 + 0] = f2bf(v.x);
        til[r][c4 * 4 + 1] = f2bf(v.y);
        til[r][c4 * 4 + 2] = f2bf(v.z);
        til[r][c4 * 4 + 3] = f2bf(v.w);
    }
    __syncthreads();
#pragma unroll
    for (int i = 0; i < 4; i++) {
        int idx = i * 256 + tid;
        int k4l = idx >> 6, nl = idx & 63;
        ush t0 = til[nl][k4l * 4 + 0], t1 = til[nl][k4l * 4 + 1];
        ush t2 = til[nl][k4l * 4 + 2], t3 = til[nl][k4l * 4 + 3];
        uint2 o;
        o.x = (unsigned)t0 | ((unsigned)t1 << 16);
        o.y = (unsigned)t2 | ((unsigned)t3 << 16);
        dst[(size_t)(k0 / 4 + k4l) * 512 + n0 + nl] = o;
    }
}

// gather embeddings -> bf16: xall[(t*256+m)*512+:]
__global__ __launch_bounds__(128) void gather_kernel(const float* __restrict__ embed_w,
                                                     const int* __restrict__ seq,
                                                     ush* __restrict__ xall) {
    int item = blockIdx.x;           // t*256 + m
    int t = item >> 8, m = item & 255;
    int row = seq[m * LL + t];
    float4 v = ((const float4*)(embed_w + (size_t)row * HH))[threadIdx.x];
    uint2 o;
    o.x = pack2(v.x, v.y);
    o.y = pack2(v.z, v.w);
    ((uint2*)(xall + (size_t)item * HH))[threadIdx.x] = o;
}

// ---------------------------------------------------------------------------
// enc transpose+convert: enc fp32 [b][c=512][s=128] -> enc_t bf16 [b*128+s][c=512]
__global__ __launch_bounds__(256) void enc_conv(const float* __restrict__ enc,
                                                ush* __restrict__ enc_t) {
    int b = blockIdx.x, cg = blockIdx.y;
    int c0 = cg * 128;
    __shared__ ush tile[128][130];
    const float* src = enc + ((size_t)b * 512 + c0) * 128;
#pragma unroll
    for (int i = 0; i < 16; i++) {
        int lin = i * 256 + threadIdx.x;     // float4 units over 128c x 32(s4)
        int cl = lin >> 5, s4 = lin & 31;
        float4 v = ((const float4*)(src + (size_t)cl * 128))[s4];
        tile[s4 * 4 + 0][cl] = f2bf(v.x);
        tile[s4 * 4 + 1][cl] = f2bf(v.y);
        tile[s4 * 4 + 2][cl] = f2bf(v.z);
        tile[s4 * 4 + 3][cl] = f2bf(v.w);
    }
    __syncthreads();
#pragma unroll
    for (int i = 0; i < 16; i++) {
        int lin = i * 256 + threadIdx.x;     // uint2 units over 128s x 32(c4)
        int sl = lin >> 5, c4 = lin & 31;
        ush a0 = tile[sl][c4 * 4 + 0], a1 = tile[sl][c4 * 4 + 1];
        ush a2 = tile[sl][c4 * 4 + 2], a3 = tile[sl][c4 * 4 + 3];
        uint2 o;
        o.x = (unsigned)a0 | ((unsigned)a1 << 16);
        o.y = (unsigned)a2 | ((unsigned)a3 << 16);
        ((uint2*)(enc_t + ((size_t)b * 128 + sl) * 512 + c0))[c4] = o;
    }
}

// ---------------------------------------------------------------------------
// Ws GEMM v3: 512 thr, 8 waves (wave = 64m x 32n), block tile 128m x 128n.
// grid (256, 4). K=512, 1-deep k-step prefetch.
__global__ __launch_bounds__(512) void ws_v3(const ush* __restrict__ enc_t,
                                             const ush* __restrict__ Wb,
                                             const float* __restrict__ bias,
                                             ush* __restrict__ Ws_bf) {
    int tid = threadIdx.x;
    int wave = tid >> 6, lane = tid & 63;
    int quad = lane >> 4, l16 = lane & 15;
    int m0 = blockIdx.x * 128 + (wave & 1) * 64;
    int n0 = blockIdx.y * 128 + (wave >> 1) * 32;
    const ush* ap = enc_t + (size_t)(m0 + l16) * 512 + quad * 8;
    const ush* bp = Wb + (size_t)(n0 + l16) * 512 + quad * 8;
    f32x4 acc[4][2];
#pragma unroll
    for (int f = 0; f < 4; f++)
#pragma unroll
        for (int s = 0; s < 2; s++) acc[f][s] = (f32x4){0.f, 0.f, 0.f, 0.f};
    short8 ac[4], bc[2], an[4], bn[2];
#pragma unroll
    for (int f = 0; f < 4; f++) ac[f] = *(const short8*)(ap + (size_t)f * 16 * 512);
#pragma unroll
    for (int s = 0; s < 2; s++) bc[s] = *(const short8*)(bp + (size_t)s * 16 * 512);
#pragma unroll
    for (int ks = 0; ks < 16; ks++) {
        if (ks < 15) {
            int k = (ks + 1) * 32;
#pragma unroll
            for (int f = 0; f < 4; f++)
                an[f] = *(const short8*)(ap + (size_t)f * 16 * 512 + k);
#pragma unroll
            for (int s = 0; s < 2; s++)
                bn[s] = *(const short8*)(bp + (size_t)s * 16 * 512 + k);
        }
#pragma unroll
        for (int f = 0; f < 4; f++)
#pragma unroll
            for (int s = 0; s < 2; s++)
                acc[f][s] = __builtin_amdgcn_mfma_f32_16x16x32_bf16(ac[f], bc[s], acc[f][s], 0, 0, 0);
        if (ks < 15) {
#pragma unroll
            for (int f = 0; f < 4; f++) ac[f] = an[f];
#pragma unroll
            for (int s = 0; s < 2; s++) bc[s] = bn[s];
        }
    }
#pragma unroll
    for (int s = 0; s < 2; s++) {
        int n = n0 + s * 16 + l16;
        float bs = bias[n];
#pragma unroll
        for (int f = 0; f < 4; f++)
#pragma unroll
            for (int r = 0; r < 4; r++) {
                int m = m0 + f * 16 + quad * 4 + r;
                Ws_bf[(size_t)m * HH + n] = f2bf(acc[f][s][r] + bs);
            }
    }
}

// ---------------------------------------------------------------------------
// Single-fragment prefetched MFMA pipeline (NSTEP k-steps of 32, 16n cols).
template <int NSTEP>
__device__ __forceinline__ void segk1(const ush* __restrict__ ap,
                                      const ush* __restrict__ bp, f32x4& a0) {
    short8 as[4], bs[4];
    constexpr int PRE = NSTEP < 4 ? NSTEP : 4;
#pragma unroll
    for (int i = 0; i < PRE; i++) {
        as[i] = *(const short8*)(ap + 32 * i);
        bs[i] = *(const short8*)(bp + 32 * i);
    }
#pragma unroll
    for (int i = 0; i < NSTEP; i++) {
        const int sl = i & 3;
        a0 = __builtin_amdgcn_mfma_f32_16x16x32_bf16(as[sl], bs[sl], a0, 0, 0, 0);
        if (i + 4 < NSTEP) {
            as[sl] = *(const short8*)(ap + 32 * (i + 4));
            bs[sl] = *(const short8*)(bp + 32 * (i + 4));
        }
    }
}

// ---------------------------------------------------------------------------
// Fused GRU v3: block tile 16m x 16n, 512 thr / 8 waves, grid (16, 32).
// K-work balanced across waves into 14 LDS slots:
//  r = s0+s1+s2+s3, z = s4+s5+s6+s7, n_i = s8+s9, n_h = s10+s11+s12+s13.
struct GruEnt { const ush* x; const ush* w; int wst; int nks; int slot; };
struct GruArgs { GruEnt e[8][2]; int zmask; };

__global__ __launch_bounds__(512) void gru_fused(GruArgs A,
                                                 const float* __restrict__ h_prev,
                                                 const float* __restrict__ bih,
                                                 const float* __restrict__ bhh,
                                                 float* __restrict__ h_out,
                                                 ush* __restrict__ h_out_bf) {
    int tid = threadIdx.x;
    int wave = __builtin_amdgcn_readfirstlane(tid >> 6);
    int lane = tid & 63, quad = lane >> 4, l16 = lane & 15;
    int m0 = blockIdx.x * 16, n0 = blockIdx.y * 16;
    __shared__ float gbuf[14][16][16];
    if (tid < 256 && A.zmask) {
        int mi = tid >> 4, ni = tid & 15;
#pragma unroll
        for (int s = 0; s < 14; s++)
            if ((A.zmask >> s) & 1) gbuf[s][mi][ni] = 0.0f;
    }
#pragma unroll
    for (int e = 0; e < 2; e++) {
        GruEnt ent = A.e[wave][e];
        if (ent.nks == 0) continue;
        f32x4 a0 = (f32x4){0.f, 0.f, 0.f, 0.f};
        const ush* ap = ent.x + (size_t)(m0 + l16) * 512 + quad * 8;
        const ush* bp = ent.w + (size_t)(n0 + l16) * ent.wst + quad * 8;
        if (ent.nks == 16)      segk1<16>(ap, bp, a0);
        else if (ent.nks == 12) segk1<12>(ap, bp, a0);
        else if (ent.nks == 8)  segk1<8>(ap, bp, a0);
        else                    segk1<4>(ap, bp, a0);
#pragma unroll
        for (int r = 0; r < 4; r++)
            gbuf[ent.slot][quad * 4 + r][l16] = a0[r];
    }
    __syncthreads();
    if (tid < 256) {
        int mi = tid >> 4, ni = tid & 15;
        int n = n0 + ni;
        size_t off = (size_t)(m0 + mi) * HH + n;
        float rr = sigm(gbuf[0][mi][ni] + gbuf[1][mi][ni] + gbuf[2][mi][ni] +
                        gbuf[3][mi][ni] + bih[n] + bhh[n]);
        float zf = sigm(gbuf[4][mi][ni] + gbuf[5][mi][ni] + gbuf[6][mi][ni] +
                        gbuf[7][mi][ni] + bih[512 + n] + bhh[512 + n]);
        float na = tanhf(gbuf[8][mi][ni] + gbuf[9][mi][ni] + bih[1024 + n] +
                         rr * (gbuf[10][mi][ni] + gbuf[11][mi][ni] +
                               gbuf[12][mi][ni] + gbuf[13][mi][ni] + bhh[1024 + n]));
        float hp = h_prev[off];
        float ho = (1.0f - zf) * na + zf * hp;
        h_out[off] = ho;
        h_out_bf[off] = f2bf(ho);
    }
}

// ---------------------------------------------------------------------------
// uaf: u-proj + attention + fc, fused. One block per batch item, 512 thr.
// u[n] = h1 . U[n,:] + Ub   (matvec, transpose-packed wUt)
// scores/softmax/ctx as attn3; ctx kept fp32 in LDS
// y[n] = relu([ctx|h1] . fc_w[n,:] + b)  (matvec, transpose-packed wFcT)
__global__ __launch_bounds__(512) void uaf(const float* __restrict__ h1f,
                                           const uint2* __restrict__ wUt,
                                           const float* __restrict__ Ub,
                                           const float* __restrict__ vw,
                                           const ush* __restrict__ Ws_bf,
                                           const ush* __restrict__ enc_t,
                                           const uint2* __restrict__ wFcT,
                                           const float* __restrict__ fc_b,
                                           ush* __restrict__ y_bf,
                                           ush* __restrict__ ys_bf) {
    int b = blockIdx.x;
    int tid = threadIdx.x;
    int wave = tid >> 6, lane = tid & 63;
    int hi = lane >> 4, li = lane & 15;
    __shared__ float h1s[512];
    __shared__ float u_lds[512];
    __shared__ float ctx[512];
    __shared__ float a[SS];
    __shared__ float part[8][512];

    h1s[tid] = h1f[(size_t)b * HH + tid];
    __syncthreads();

    // ---- u matvec
    {
        float acc = Ub[tid];
        const uint2* wp = wUt + tid;
#pragma unroll 8
        for (int kq = 0; kq < 128; kq++) {
            uint2 pr = wp[(size_t)kq * 512];
            float x0 = h1s[kq * 4 + 0], x1 = h1s[kq * 4 + 1];
            float x2 = h1s[kq * 4 + 2], x3 = h1s[kq * 4 + 3];
            acc += bfl(pr.x) * x0 + bfh(pr.x) * x1 + bfl(pr.y) * x2 + bfh(pr.y) * x3;
        }
        u_lds[tid] = acc;
    }
    __syncthreads();

    // ---- scores
    float ur[4][8], vr[4][8];
#pragma unroll
    for (int p = 0; p < 4; p++) {
        float4 u0 = *(const float4*)(&u_lds[p * 128 + li * 8]);
        float4 u1 = *(const float4*)(&u_lds[p * 128 + li * 8 + 4]);
        const float* vp = vw + p * 128 + li * 8;
        float4 v0 = *(const float4*)(vp);
        float4 v1 = *(const float4*)(vp + 4);
        ur[p][0] = u0.x; ur[p][1] = u0.y; ur[p][2] = u0.z; ur[p][3] = u0.w;
        ur[p][4] = u1.x; ur[p][5] = u1.y; ur[p][6] = u1.z; ur[p][7] = u1.w;
        vr[p][0] = v0.x; vr[p][1] = v0.y; vr[p][2] = v0.z; vr[p][3] = v0.w;
        vr[p][4] = v1.x; vr[p][5] = v1.y; vr[p][6] = v1.z; vr[p][7] = v1.w;
    }
    const ush* wsb = Ws_bf + (size_t)b * SS * HH;
#pragma unroll
    for (int pass = 0; pass < 4; pass++) {
        int s = pass * 32 + wave * 4 + hi;
        float acc = 0.0f;
#pragma unroll
        for (int p = 0; p < 4; p++) {
            short8 rv = *(const short8*)(wsb + (size_t)s * HH + p * 128 + li * 8);
#pragma unroll
            for (int j = 0; j < 8; j++) {
                float e = bf2f((ush)rv[j]) + ur[p][j];
                acc += fmaxf(e, 0.0f) * vr[p][j];
            }
        }
#pragma unroll
        for (int off = 1; off < 16; off <<= 1) acc += __shfl_xor(acc, off);
        if (li == 0) a[s] = acc;
    }
    __syncthreads();

    // ---- softmax
    if (wave == 0) {
        float s0v = a[lane], s1v = a[lane + 64];
        float m = wave_max(fmaxf(s0v, s1v));
        float e0 = expf(s0v - m), e1 = expf(s1v - m);
        float ssum = wave_sum(e0 + e1);
        float inv = 1.0f / ssum;
        a[lane] = e0 * inv;
        a[lane + 64] = e1 * inv;
    }
    __syncthreads();

    // ---- ctx: wave w handles s = w*16..w*16+15; lane owns c-octet lane*8.
    {
        float c8[8];
#pragma unroll
        for (int j = 0; j < 8; j++) c8[j] = 0.0f;
        const ush* ebt = enc_t + (size_t)b * SS * 512;
#pragma unroll
        for (int i = 0; i < 16; i++) {
            int s = wave * 16 + i;
            float as = a[s];
            short8 ev = *(const short8*)(ebt + (size_t)s * 512 + lane * 8);
#pragma unroll
            for (int j = 0; j < 8; j++) c8[j] += as * bf2f((ush)ev[j]);
        }
        *(float4*)(&part[wave][lane * 8])     = (float4){c8[0], c8[1], c8[2], c8[3]};
        *(float4*)(&part[wave][lane * 8 + 4]) = (float4){c8[4], c8[5], c8[6], c8[7]};
    }
    __syncthreads();
    {
        float sum = 0.0f;
#pragma unroll
        for (int w = 0; w < 8; w++) sum += part[w][tid];
        ctx[tid] = sum;
    }
    __syncthreads();

    // ---- fc matvec: k 0..511 = ctx, 512..1023 = h1
    {
        float acc = fc_b[tid];
        const uint2* wp = wFcT + tid;
#pragma unroll 8
        for (int kq = 0; kq < 128; kq++) {
            uint2 pr = wp[(size_t)kq * 512];
            float x0 = ctx[kq * 4 + 0], x1 = ctx[kq * 4 + 1];
            float x2 = ctx[kq * 4 + 2], x3 = ctx[kq * 4 + 3];
            acc += bfl(pr.x) * x0 + bfh(pr.x) * x1 + bfl(pr.y) * x2 + bfh(pr.y) * x3;
        }
#pragma unroll 8
        for (int kq = 128; kq < 256; kq++) {
            uint2 pr = wp[(size_t)kq * 512];
            int k = kq * 4 - 512;
            float x0 = h1s[k + 0], x1 = h1s[k + 1];
            float x2 = h1s[k + 2], x3 = h1s[k + 3];
            acc += bfl(pr.x) * x0 + bfh(pr.x) * x1 + bfl(pr.y) * x2 + bfh(pr.y) * x3;
        }
        float v = fmaxf(acc, 0.0f);
        ush bb = f2bf(v);
        y_bf[(size_t)b * HH + tid] = bb;
        if (ys_bf) ys_bf[(size_t)b * HH + tid] = bb;
    }
}

// ---------------------------------------------------------------------------
// Fused cls GEMM + log-softmax NLL. Grid 368 (16 items each), 256 thr.
__global__ __launch_bounds__(256) void cls_fused(const ush* __restrict__ ys,
                                                 const ush* __restrict__ wCls,
                                                 const float* __restrict__ cls_b,
                                                 const int* __restrict__ seq,
                                                 float* __restrict__ acc) {
    int tid = threadIdx.x;
    int wave = tid >> 6, lane = tid & 63;
    int quad = lane >> 4, l16 = lane & 15;
    int m0 = blockIdx.x * 16;
    f32x4 a4[4];
#pragma unroll
    for (int s = 0; s < 4; s++) a4[s] = (f32x4){0.f, 0.f, 0.f, 0.f};
    const ush* ap = ys + (size_t)(m0 + l16) * 512 + wave * 128 + quad * 8;
    const ush* bp = wCls + (size_t)l16 * 512 + wave * 128 + quad * 8;
#pragma unroll
    for (int ks = 0; ks < 4; ks++) {
        short8 av = *(const short8*)(ap + ks * 32);
#pragma unroll
        for (int s = 0; s < 4; s++) {
            short8 bv = *(const short8*)(bp + (size_t)s * 16 * 512 + ks * 32);
            a4[s] = __builtin_amdgcn_mfma_f32_16x16x32_bf16(av, bv, a4[s], 0, 0, 0);
        }
    }
    __shared__ float gbuf[4][16][64];
    __shared__ float red[8];
#pragma unroll
    for (int s = 0; s < 4; s++)
#pragma unroll
        for (int r = 0; r < 4; r++)
            gbuf[wave][quad * 4 + r][s * 16 + l16] = a4[s][r];
    __syncthreads();
    float lsum = 0.0f, lcnt = 0.0f;
#pragma unroll
    for (int ii = 0; ii < 4; ii++) {
        int mi = wave * 4 + ii;
        int item = m0 + mi;
        int t = item >> 8, b = item & 255;
        float v = gbuf[0][mi][lane] + gbuf[1][mi][lane] + gbuf[2][mi][lane] +
                  gbuf[3][mi][lane] + cls_b[lane];
        float mx = wave_max(v);
        float e = expf(v - mx);
        float ssum = wave_sum(e);
        int label = seq[b * LL + t + 1];
        float vl = __shfl(v, label);
        if (label > 0) {
            lsum += -(vl - mx - logf(ssum));
            lcnt += 1.0f;
        }
    }
    if (lane == 0) { red[wave] = lsum; red[4 + wave] = lcnt; }
    __syncthreads();
    if (tid == 0) {
        atomicAdd(&acc[0], red[0] + red[1] + red[2] + red[3]);
        atomicAdd(&acc[1], red[4] + red[5] + red[6] + red[7]);
    }
}

__global__ void final_kernel(const float* __restrict__ acc, float* __restrict__ out) {
    if (threadIdx.x == 0) out[0] = acc[0] / acc[1];
}

// ---------------------------------------------------------------------------
extern "C" void kernel_launch(void* const* d_in, const int* in_sizes, int n_in,
                              void* d_out, int out_size, void* d_ws, size_t ws_size,
                              hipStream_t stream) {
    const float* enc        = (const float*)d_in[0];
    const int*   seq        = (const int*)d_in[1];
    const float* embed_w    = (const float*)d_in[3];
    const float* init_state = (const float*)d_in[4];
    const float* attn_W_w   = (const float*)d_in[5];
    const float* attn_W_b   = (const float*)d_in[6];
    const float* attn_U_w   = (const float*)d_in[7];
    const float* attn_U_b   = (const float*)d_in[8];
    const float* attn_v_w   = (const float*)d_in[9];
    const float* fc_w       = (const float*)d_in[11];
    const float* fc_b       = (const float*)d_in[12];
    const float* cls_w      = (const float*)d_in[13];
    const float* cls_b      = (const float*)d_in[14];
    const float* g0_wih     = (const float*)d_in[15];
    const float* g0_whh     = (const float*)d_in[16];
    const float* g0_bih     = (const float*)d_in[17];
    const float* g0_bhh     = (const float*)d_in[18];
    const float* g1_wih     = (const float*)d_in[19];
    const float* g1_whh     = (const float*)d_in[20];
    const float* g1_bih     = (const float*)d_in[21];
    const float* g1_bhh     = (const float*)d_in[22];
    float* out = (float*)d_out;

    float* ws = (float*)d_ws;
    size_t o = 0;
    ush* Ws_bf   = (ush*)(ws + o); o += (size_t)BB * SS * HH / 2;
    ush* enc_t   = (ush*)(ws + o); o += (size_t)BB * CC * SS / 2;
    ush* ys_bf   = (ush*)(ws + o); o += (size_t)(LL - 1) * BB * HH / 2;
    ush* xall_bf = (ush*)(ws + o); o += (size_t)(LL - 1) * BB * HH / 2;
    // bf16 weights
    ush* wWb  = (ush*)(ws + o); o += 262144 / 2;
    ush* wCls = (ush*)(ws + o); o += 32768 / 2;
    ush* wG0i = (ush*)(ws + o); o += 1572864 / 2;
    ush* wG0h = (ush*)(ws + o); o += 786432 / 2;
    ush* wG1i = (ush*)(ws + o); o += 786432 / 2;
    ush* wG1h = (ush*)(ws + o); o += 786432 / 2;
    uint2* wUt  = (uint2*)(ws + o); o += 131072;   // [128][512] uint2
    uint2* wFcT = (uint2*)(ws + o); o += 262144;   // [256][512] uint2
    // fp32 loop buffers
    float* h0a  = ws + o; o += (size_t)BB * HH;
    float* h0b  = ws + o; o += (size_t)BB * HH;
    float* h1a  = ws + o; o += (size_t)BB * HH;
    float* h1b  = ws + o; o += (size_t)BB * HH;
    float* acc  = ws + o; o += 256;
    ush* h0a_bf = (ush*)(ws + o); o += (size_t)BB * HH / 2;
    ush* h0b_bf = (ush*)(ws + o); o += (size_t)BB * HH / 2;
    ush* h1a_bf = (ush*)(ws + o); o += (size_t)BB * HH / 2;
    ush* h1b_bf = (ush*)(ws + o); o += (size_t)BB * HH / 2;
    ush* y_bf   = (ush*)(ws + o); o += (size_t)BB * HH / 2;

    init_kernel<<<512, 256, 0, stream>>>(init_state, h0a, h1a, h0a_bf, h1a_bf, acc);
    {
        CvArgs cv{};
        cv.src[0] = attn_W_w; cv.dst[0] = wWb;
        cv.src[1] = cls_w;    cv.dst[1] = wCls;
        cv.src[2] = g0_wih;   cv.dst[2] = wG0i;
        cv.src[3] = g0_whh;   cv.dst[3] = wG0h;
        cv.src[4] = g1_wih;   cv.dst[4] = wG1i;
        cv.src[5] = g1_whh;   cv.dst[5] = wG1h;
        cv.end[0] = 256; cv.end[1] = 288; cv.end[2] = 1824;
        cv.end[3] = 2592; cv.end[4] = 3360; cv.end[5] = 4128;
        conv_multi<<<4128, 256, 0, stream>>>(cv);
    }
    tp_conv<<<dim3(8, 8), 256, 0, stream>>>(attn_U_w, wUt, 512);
    tp_conv<<<dim3(8, 16), 256, 0, stream>>>(fc_w, wFcT, 1024);
    enc_conv<<<dim3(256, 4), 256, 0, stream>>>(enc, enc_t);
    gather_kernel<<<(LL - 1) * BB, 128, 0, stream>>>(embed_w, seq, xall_bf);
    ws_v3<<<dim3(256, 4), 512, 0, stream>>>(enc_t, wWb, attn_W_b, Ws_bf);

    auto E = [](GruArgs& a, int w, int e, const ush* x, const ush* wp, int wst,
                int nks, int slot) {
        a.e[w][e].x = x; a.e[w][e].w = wp; a.e[w][e].wst = wst;
        a.e[w][e].nks = nks; a.e[w][e].slot = slot;
    };
    auto gru0_args = [&](const ush* y, const ush* x, const ush* h0) {
        GruArgs a{};
        E(a, 0, 0, y,        wG0i,                              1024, 16, 0);   // r <- y
        E(a, 1, 0, x,        wG0i + 512,                        1024, 16, 1);   // r <- x
        E(a, 2, 0, h0,       wG0h,                               512, 16, 2);   // r <- h
        E(a, 3, 0, y,        wG0i + (size_t)512 * 1024,         1024, 16, 4);   // z <- y
        E(a, 4, 0, x,        wG0i + (size_t)512 * 1024 + 512,   1024, 16, 5);   // z <- x
        E(a, 5, 0, h0,       wG0h + (size_t)512 * 512,           512, 16, 6);   // z <- h
        E(a, 6, 0, y,        wG0i + (size_t)1024 * 1024,        1024, 16, 8);   // ni <- y
        E(a, 7, 0, x,        wG0i + (size_t)1024 * 1024 + 512,  1024, 16, 9);   // ni <- x
        E(a, 2, 1, h0,       wG0h + (size_t)1024 * 512,          512,  4, 10);  // nh [0:128]
        E(a, 3, 1, h0 + 128, wG0h + (size_t)1024 * 512 + 128,    512,  4, 11);  // nh [128:256]
        E(a, 4, 1, h0 + 256, wG0h + (size_t)1024 * 512 + 256,    512,  4, 12);  // nh [256:384]
        E(a, 5, 1, h0 + 384, wG0h + (size_t)1024 * 512 + 384,    512,  4, 13);  // nh [384:512]
        a.zmask = (1 << 3) | (1 << 7);
        return a;
    };
    auto gru1_args = [&](const ush* hi_, const ush* hh) {
        GruArgs a{};
        E(a, 0, 0, hi_,       wG1i,                             512, 12, 0);    // r<-i [0:384]
        E(a, 1, 0, hh,        wG1h,                             512, 12, 2);    // r<-h [0:384]
        E(a, 2, 0, hi_,       wG1i + (size_t)512 * 512,         512, 12, 4);    // z<-i [0:384]
        E(a, 3, 0, hh,        wG1h + (size_t)512 * 512,         512, 12, 6);    // z<-h [0:384]
        E(a, 4, 0, hi_,       wG1i + (size_t)1024 * 512,        512,  8, 8);    // ni [0:256]
        E(a, 4, 1, hi_ + 384, wG1i + 384,                       512,  4, 1);    // r<-i [384:512]
        E(a, 5, 0, hi_ + 256, wG1i + (size_t)1024 * 512 + 256,  512,  8, 9);    // ni [256:512]
        E(a, 5, 1, hh + 384,  wG1h + 384,                       512,  4, 3);    // r<-h [384:512]
        E(a, 6, 0, hh,        wG1h + (size_t)1024 * 512,        512,  8, 10);   // nh [0:256]
        E(a, 6, 1, hi_ + 384, wG1i + (size_t)512 * 512 + 384,   512,  4, 5);    // z<-i [384:512]
        E(a, 7, 0, hh + 256,  wG1h + (size_t)1024 * 512 + 256,  512,  8, 11);   // nh [256:512]
        E(a, 7, 1, hh + 384,  wG1h + (size_t)512 * 512 + 384,   512,  4, 7);    // z<-h [384:512]
        a.zmask = (1 << 12) | (1 << 13);
        return a;
    };

    // ---- prologue: y0 = out_proj(attn(h1), h1)
    uaf<<<BB, 512, 0, stream>>>(h1a, wUt, attn_U_b, attn_v_w, Ws_bf, enc_t,
                                wFcT, fc_b, y_bf, nullptr);

    float* h0_in = h0a; float* h0_out = h0b;
    float* h1_in = h1a; float* h1_out = h1b;
    ush* h0_in_bf = h0a_bf; ush* h0_out_bf = h0b_bf;
    ush* h1_in_bf = h1a_bf; ush* h1_out_bf = h1b_bf;
    for (int t = 0; t < LL - 1; t++) {
        gru_fused<<<dim3(16, 32), 512, 0, stream>>>(
            gru0_args(y_bf, xall_bf + (size_t)t * BB * HH, h0_in_bf),
            h0_in, g0_bih, g0_bhh, h0_out, h0_out_bf);
        gru_fused<<<dim3(16, 32), 512, 0, stream>>>(
            gru1_args(h0_out_bf, h1_in_bf),
            h1_in, g1_bih, g1_bhh, h1_out, h1_out_bf);
        uaf<<<BB, 512, 0, stream>>>(h1_out, wUt, attn_U_b, attn_v_w, Ws_bf, enc_t,
                                    wFcT, fc_b, y_bf, ys_bf + (size_t)t * BB * HH);
        float* tmp;
        tmp = h0_in; h0_in = h0_out; h0_out = tmp;
        tmp = h1_in; h1_in = h1_out; h1_out = tmp;
        ush* tb;
        tb = h0_in_bf; h0_in_bf = h0_out_bf; h0_out_bf = tb;
        tb = h1_in_bf; h1_in_bf = h1_out_bf; h1_out_bf = tb;
    }

    cls_fused<<<368, 256, 0, stream>>>(ys_bf, wCls, cls_b, seq, acc);
    final_kernel<<<1, 1, 0, stream>>>(acc, out);
}